// Round 5
// baseline (420.716 us; speedup 1.0000x reference)
//
#include <hip/hip_runtime.h>

#define BT_ (8 * 2048)
#define T_  2048
#define H_  64
#define NTICK 512   // 8 batches x 64 q-tiles of 32 rows

// ---------------------------------------------------------------------------
// Kernel 1: fused QKV projection (f32 exact)
// x:[16384,1024] @ W{q,k,v}:[1024,64] -> qkv ws: Q|K|V each [16384,64]
// grid 512, block 256 (2 blocks/CU -> 8 waves/CU). Block tile: 32 rows x 192
// cols. Thread tile: 2r x 12c. K staged in chunks of 32.
// Strides 33/196: transpose writes 2-way (free), reads 2-way.
// ---------------------------------------------------------------------------
__global__ __launch_bounds__(256) void qkv_proj(
    const float* __restrict__ x,
    const float* __restrict__ Wq,
    const float* __restrict__ Wk,
    const float* __restrict__ Wv,
    float* __restrict__ qkv) {
  __shared__ float xT[32][33];    // [k][row]
  __shared__ float wl[32][196];   // [k][192 cols]

  const int tid = threadIdx.x;
  const int tx = tid & 15;   // col group: cols tx*12 .. +11
  const int ty = tid >> 4;   // row group: rows ty*2 .. +1
  const int row0 = blockIdx.x * 32;

  float acc[2][12];
#pragma unroll
  for (int r = 0; r < 2; ++r)
#pragma unroll
    for (int c = 0; c < 12; ++c) acc[r][c] = 0.f;

  for (int kc = 0; kc < 1024; kc += 32) {
    // stage x chunk transposed: 32 rows x 32 k = 256 float4, 1/thread
    {
      int r = tid >> 3;
      int k4 = (tid & 7) * 4;
      const float4 v = *reinterpret_cast<const float4*>(
          &x[(size_t)(row0 + r) * 1024 + kc + k4]);
      xT[k4 + 0][r] = v.x;
      xT[k4 + 1][r] = v.y;
      xT[k4 + 2][r] = v.z;
      xT[k4 + 3][r] = v.w;
    }
    // stage W chunk: 32 k x (64 q | 64 k | 64 v)
    {
      const float* wp[3] = {Wq, Wk, Wv};
#pragma unroll
      for (int m = 0; m < 3; ++m) {
#pragma unroll
        for (int i = 0; i < 2; ++i) {
          int idx = tid + i * 256;
          int r = idx >> 4;
          int h4 = (idx & 15) * 4;
          const float4 v = *reinterpret_cast<const float4*>(
              &wp[m][(size_t)(kc + r) * 64 + h4]);
          *reinterpret_cast<float4*>(&wl[r][m * 64 + h4]) = v;
        }
      }
    }
    __syncthreads();

#pragma unroll
    for (int kk = 0; kk < 32; ++kk) {
      const float2 xv = *reinterpret_cast<const float2*>(&xT[kk][ty * 2]);
      const float4 w0 = *reinterpret_cast<const float4*>(&wl[kk][tx * 12 + 0]);
      const float4 w1 = *reinterpret_cast<const float4*>(&wl[kk][tx * 12 + 4]);
      const float4 w2 = *reinterpret_cast<const float4*>(&wl[kk][tx * 12 + 8]);
      const float xr[2] = {xv.x, xv.y};
      const float wr[12] = {w0.x, w0.y, w0.z, w0.w, w1.x, w1.y, w1.z, w1.w,
                            w2.x, w2.y, w2.z, w2.w};
#pragma unroll
      for (int r = 0; r < 2; ++r)
#pragma unroll
        for (int c = 0; c < 12; ++c)
          acc[r][c] = fmaf(xr[r], wr[c], acc[r][c]);
    }
    __syncthreads();
  }

  // epilogue: scatter 2x12 into Q/K/V planes of ws
#pragma unroll
  for (int r = 0; r < 2; ++r) {
#pragma unroll
    for (int g = 0; g < 3; ++g) {
      const int col = tx * 12 + g * 4;
      const int m = col >> 6;     // 0=Q 1=K 2=V (float4 never crosses a plane)
      const int h = col & 63;
      float4 v = make_float4(acc[r][g * 4 + 0], acc[r][g * 4 + 1],
                             acc[r][g * 4 + 2], acc[r][g * 4 + 3]);
      *reinterpret_cast<float4*>(
          &qkv[(size_t)m * BT_ * H_ + (size_t)(row0 + ty * 2 + r) * H_ + h]) = v;
    }
  }
}

// ---------------------------------------------------------------------------
// Kernel 2: causal flash attention (f32 exact, online softmax)
// PERSISTENT blocks (768 = 3/CU) + atomic ticket queue over 512 q-tiles,
// tickets ordered LPT-descending -> near-perfect load balance.
// Per k-tile: S in-register (2 q-rows x 4 k-cols/thread), shfl softmax,
// PV via __shfl broadcast of P (no pT LDS roundtrip). Strides 33/65:
// all LDS accesses <=2-way.
// ---------------------------------------------------------------------------
__global__ __launch_bounds__(256) void attn_fwd(
    const float* __restrict__ qkv, float* __restrict__ out,
    unsigned int* __restrict__ ctr) {
  __shared__ float qT[64][33];  // [h][qrow]  (pre-scaled by 1/32)
  __shared__ float kT[64][65];  // [h][krow]
  __shared__ float vl[64][65];  // [krow][h]
  __shared__ unsigned int sticket;

  const int tid = threadIdx.x;
  const int tx = tid & 15;    // k-cols tx*4 .. +3  /  h-cols tx*4 .. +3
  const int ty = tid >> 4;    // q-rows ty*2 .. +1
  const int lane = tid & 63;

  const float* Q = qkv;
  const float* K = qkv + (size_t)BT_ * H_;
  const float* V = qkv + (size_t)2 * BT_ * H_;

  while (true) {
    if (tid == 0) sticket = atomicAdd(ctr, 1u);
    __syncthreads();          // publishes sticket; also tile boundary barrier
    const unsigned int t = sticket;
    if (t >= (unsigned)NTICK) break;
    const int b = (int)(t & 7);
    const int qt = 63 - (int)(t >> 3);   // LPT: biggest tiles first
    const int r0 = qt * 32;

    // stage q tile transposed, folding the 1/sqrt(C)=1/32 scale
#pragma unroll
    for (int i = 0; i < 2; ++i) {
      int idx = tid + i * 256;
      int r = idx >> 4;
      int h4 = (idx & 15) * 4;
      float4 v = *reinterpret_cast<const float4*>(
          &Q[((size_t)b * T_ + r0 + r) * H_ + h4]);
      qT[h4 + 0][r] = v.x * 0.03125f;
      qT[h4 + 1][r] = v.y * 0.03125f;
      qT[h4 + 2][r] = v.z * 0.03125f;
      qT[h4 + 3][r] = v.w * 0.03125f;
    }
    // qT visibility covered by the first k-tile's __syncthreads.

    float m0 = -1e30f, m1 = -1e30f, l0 = 0.f, l1 = 0.f;
    float o0[4] = {0, 0, 0, 0}, o1[4] = {0, 0, 0, 0};

    const int nkt = qt / 2 + 1;
    for (int kt = 0; kt < nkt; ++kt) {
      // stage K (transposed) and V (row-major) tiles
#pragma unroll
      for (int i = 0; i < 4; ++i) {
        int idx = tid + i * 256;
        int j = idx >> 4;
        int h4 = (idx & 15) * 4;
        size_t g = ((size_t)b * T_ + kt * 64 + j) * H_ + h4;
        float4 kv = *reinterpret_cast<const float4*>(&K[g]);
        kT[h4 + 0][j] = kv.x;
        kT[h4 + 1][j] = kv.y;
        kT[h4 + 2][j] = kv.z;
        kT[h4 + 3][j] = kv.w;
        *reinterpret_cast<float4*>(&vl[j][h4]) =
            *reinterpret_cast<const float4*>(&V[g]);
      }
      __syncthreads();

      // S = q . k  (2 rows x 4 cols per thread)
      float s0[4] = {0, 0, 0, 0}, s1[4] = {0, 0, 0, 0};
#pragma unroll
      for (int h = 0; h < 64; ++h) {
        float2 qv = *reinterpret_cast<const float2*>(&qT[h][ty * 2]);
        float4 kv = *reinterpret_cast<const float4*>(&kT[h][tx * 4]);
        const float kr[4] = {kv.x, kv.y, kv.z, kv.w};
#pragma unroll
        for (int c = 0; c < 4; ++c) {
          s0[c] = fmaf(qv.x, kr[c], s0[c]);
          s1[c] = fmaf(qv.y, kr[c], s1[c]);
        }
      }

      // causal mask — only the diagonal k-tile can clip
      if (kt == nkt - 1) {
        const int rg = r0 + ty * 2;
#pragma unroll
        for (int c = 0; c < 4; ++c) {
          const int jg = kt * 64 + tx * 4 + c;
          if (jg > rg)     s0[c] = -1e30f;
          if (jg > rg + 1) s1[c] = -1e30f;
        }
      }

      // online softmax: row max / sum across the 16 tx lanes
      float mt0 = fmaxf(fmaxf(s0[0], s0[1]), fmaxf(s0[2], s0[3]));
      float mt1 = fmaxf(fmaxf(s1[0], s1[1]), fmaxf(s1[2], s1[3]));
#pragma unroll
      for (int d = 1; d < 16; d <<= 1) {
        mt0 = fmaxf(mt0, __shfl_xor(mt0, d));
        mt1 = fmaxf(mt1, __shfl_xor(mt1, d));
      }
      const float mn0 = fmaxf(m0, mt0), mn1 = fmaxf(m1, mt1);
      const float a0 = __expf(m0 - mn0), a1 = __expf(m1 - mn1);
      float p0[4], p1[4], sum0 = 0.f, sum1 = 0.f;
#pragma unroll
      for (int c = 0; c < 4; ++c) {
        p0[c] = __expf(s0[c] - mn0);
        p1[c] = __expf(s1[c] - mn1);
        sum0 += p0[c];
        sum1 += p1[c];
      }
#pragma unroll
      for (int d = 1; d < 16; d <<= 1) {
        sum0 += __shfl_xor(sum0, d);
        sum1 += __shfl_xor(sum1, d);
      }
      l0 = l0 * a0 + sum0;
      l1 = l1 * a1 + sum1;
      m0 = mn0;
      m1 = mn1;
#pragma unroll
      for (int c = 0; c < 4; ++c) {
        o0[c] *= a0;
        o1[c] *= a1;
      }

      // O += P . V — P broadcast via shfl from the owning lane (same ty group)
#pragma unroll 8
      for (int j = 0; j < 64; ++j) {
        const int src = (lane & 48) | (j >> 2);
        const float pj0 = __shfl(p0[j & 3], src, 64);
        const float pj1 = __shfl(p1[j & 3], src, 64);
        const float4 vv = *reinterpret_cast<const float4*>(&vl[j][tx * 4]);
        o0[0] = fmaf(pj0, vv.x, o0[0]);
        o0[1] = fmaf(pj0, vv.y, o0[1]);
        o0[2] = fmaf(pj0, vv.z, o0[2]);
        o0[3] = fmaf(pj0, vv.w, o0[3]);
        o1[0] = fmaf(pj1, vv.x, o1[0]);
        o1[1] = fmaf(pj1, vv.y, o1[1]);
        o1[2] = fmaf(pj1, vv.z, o1[2]);
        o1[3] = fmaf(pj1, vv.w, o1[3]);
      }
      __syncthreads();  // kT/vl consumed before next stage / next tile
    }

    const float inv0 = 1.0f / l0, inv1 = 1.0f / l1;
    const size_t orow = ((size_t)b * T_ + r0 + ty * 2) * H_ + tx * 4;
    *reinterpret_cast<float4*>(&out[orow]) =
        make_float4(o0[0] * inv0, o0[1] * inv0, o0[2] * inv0, o0[3] * inv0);
    *reinterpret_cast<float4*>(&out[orow + H_]) =
        make_float4(o1[0] * inv1, o1[1] * inv1, o1[2] * inv1, o1[3] * inv1);
  }
}

extern "C" void kernel_launch(void* const* d_in, const int* in_sizes, int n_in,
                              void* d_out, int out_size, void* d_ws,
                              size_t ws_size, hipStream_t stream) {
  const float* x  = (const float*)d_in[0];
  const float* Wq = (const float*)d_in[1];
  const float* Wk = (const float*)d_in[2];
  const float* Wv = (const float*)d_in[3];
  float* ws  = (float*)d_ws;   // Q | K | V planes: 3 * 16384*64 f32 = 12 MB
  float* out = (float*)d_out;
  unsigned int* ctr =
      (unsigned int*)((char*)d_ws + (size_t)3 * BT_ * H_ * sizeof(float));

  qkv_proj<<<512, 256, 0, stream>>>(x, Wq, Wk, Wv, ws);
  hipMemsetAsync(ctr, 0, sizeof(unsigned int), stream);  // ticket reset
  attn_fwd<<<768, 256, 0, stream>>>(ws, out, ctr);
}

// Round 10
// 402.760 us; speedup vs baseline: 1.0446x; 1.0446x over previous
//
#include <hip/hip_runtime.h>

#define BT_ (8 * 2048)
#define T_  2048
#define H_  64

// ws layout (float offsets):
//   [0, QKV_F)  Q | K | V planes
//   PO_F: 512 pieces x 32 rows x 64 h   partial O numerators (split tiles)
//   PM_F: 512 x 32   partial row max
//   PL_F: 512 x 32   partial row l
#define QKV_F (3 * BT_ * H_)
#define PO_F  QKV_F
#define PM_F  (PO_F + 512 * 32 * 64)
#define PL_F  (PM_F + 512 * 32)

// ---------------------------------------------------------------------------
// Kernel 1: fused QKV projection (f32 exact)
// grid 512 x 128 thr (5 blocks/CU, 10 waves/CU). Block tile 32r x 192c,
// thread tile 4r x 12c -> inner loop 4 x b128 LDS reads per 48 FMAs
// (FMA-bound). All LDS access patterns conflict-free per 8-lane phase.
// ---------------------------------------------------------------------------
__global__ __launch_bounds__(128) void qkv_proj(
    const float* __restrict__ x,
    const float* __restrict__ Wq,
    const float* __restrict__ Wk,
    const float* __restrict__ Wv,
    float* __restrict__ qkv) {
  __shared__ float xT[32][33];    // [k][row]
  __shared__ float wl[32][196];   // [k][192 cols]

  const int tid = threadIdx.x;
  const int tx = tid & 15;   // cols tx*12 .. +11
  const int ty = tid >> 4;   // rows ty*4 .. +3   (0..7)
  const int row0 = blockIdx.x * 32;

  float acc[4][12];
#pragma unroll
  for (int r = 0; r < 4; ++r)
#pragma unroll
    for (int c = 0; c < 12; ++c) acc[r][c] = 0.f;

  for (int kc = 0; kc < 1024; kc += 32) {
    // stage x chunk transposed: 32 rows x 32 k = 256 float4, 2/thread
#pragma unroll
    for (int i = 0; i < 2; ++i) {
      int idx = tid + i * 128;
      int r = idx >> 3;
      int k4 = (idx & 7) * 4;
      const float4 v = *reinterpret_cast<const float4*>(
          &x[(size_t)(row0 + r) * 1024 + kc + k4]);
      xT[k4 + 0][r] = v.x;
      xT[k4 + 1][r] = v.y;
      xT[k4 + 2][r] = v.z;
      xT[k4 + 3][r] = v.w;
    }
    // stage W chunk: 32 k x (64|64|64), 12 float4/thread
    {
      const float* wp[3] = {Wq, Wk, Wv};
#pragma unroll
      for (int m = 0; m < 3; ++m) {
#pragma unroll
        for (int i = 0; i < 4; ++i) {
          int idx = tid + i * 128;
          int r = idx >> 4;
          int h4 = (idx & 15) * 4;
          const float4 v = *reinterpret_cast<const float4*>(
              &wp[m][(size_t)(kc + r) * 64 + h4]);
          *reinterpret_cast<float4*>(&wl[r][m * 64 + h4]) = v;
        }
      }
    }
    __syncthreads();

#pragma unroll 8
    for (int kk = 0; kk < 32; ++kk) {
      const float4 xv = *reinterpret_cast<const float4*>(&xT[kk][ty * 4]);
      const float4 w0 = *reinterpret_cast<const float4*>(&wl[kk][tx * 12 + 0]);
      const float4 w1 = *reinterpret_cast<const float4*>(&wl[kk][tx * 12 + 4]);
      const float4 w2 = *reinterpret_cast<const float4*>(&wl[kk][tx * 12 + 8]);
      const float xr[4] = {xv.x, xv.y, xv.z, xv.w};
      const float wr[12] = {w0.x, w0.y, w0.z, w0.w, w1.x, w1.y, w1.z, w1.w,
                            w2.x, w2.y, w2.z, w2.w};
#pragma unroll
      for (int r = 0; r < 4; ++r)
#pragma unroll
        for (int c = 0; c < 12; ++c)
          acc[r][c] = fmaf(xr[r], wr[c], acc[r][c]);
    }
    __syncthreads();
  }

#pragma unroll
  for (int r = 0; r < 4; ++r) {
#pragma unroll
    for (int g = 0; g < 3; ++g) {
      const int col = tx * 12 + g * 4;
      const int m = col >> 6;     // float4 never crosses a Q/K/V plane
      const int h = col & 63;
      float4 v = make_float4(acc[r][g * 4 + 0], acc[r][g * 4 + 1],
                             acc[r][g * 4 + 2], acc[r][g * 4 + 3]);
      *reinterpret_cast<float4*>(
          &qkv[(size_t)m * BT_ * H_ + (size_t)(row0 + ty * 4 + r) * H_ + h]) = v;
    }
  }
}

// ---------------------------------------------------------------------------
// Kernel 2: causal flash attention, split-K for balance (f32 exact)
// grid 768 x 128 thr (3 blocks/CU, 6 waves/CU; 50 KB LDS).
// Block = one piece: qt>=32 tiles split into key-halves A (g 0..31) and
// B (g 32..63, diagonal+mask) writing (m,l,O-numerator) partials; qt<32
// unsplit (g 64..95) write out directly. Fattest pieces dispatch first.
// Thread tile 4 q-rows x 4 k-cols; QK/PV: 2 x b128 per 16 FMA (FMA-bound).
// ---------------------------------------------------------------------------
__global__ __launch_bounds__(128) void attn_fwd(
    const float* __restrict__ qkv, float* __restrict__ out,
    float* __restrict__ ws) {
  __shared__ float qT[64][33];  // [h][qrow], pre-scaled by 1/32
  __shared__ float kT[64][65];  // [h][krow]
  __shared__ float vl[64][65];  // [krow][h]
  __shared__ float pT[64][33];  // [krow][qrow]

  const int tid = threadIdx.x;
  const int tx = tid & 15;    // k-cols / h-cols tx*4 .. +3
  const int ty = tid >> 4;    // q-rows ty*4 .. +3   (0..7)
  const int b  = blockIdx.x & 7;
  const int g  = blockIdx.x >> 3;   // 0..95

  int qt, kt0, nktp, half;
  bool masked;
  if (g < 32) {                 // piece A of split tile
    qt = 63 - g;
    const int n = qt / 2 + 1;
    kt0 = 0; nktp = (n + 1) / 2; masked = false; half = 0;
  } else if (g < 64) {          // piece B (holds the diagonal)
    qt = 63 - (g - 32);
    const int n = qt / 2 + 1;
    kt0 = (n + 1) / 2; nktp = n - kt0; masked = true; half = 1;
  } else {                      // unsplit tile
    qt = 95 - g;
    kt0 = 0; nktp = qt / 2 + 1; masked = true; half = -1;
  }
  const int r0 = qt * 32;

  const float* Q = qkv;
  const float* K = qkv + (size_t)BT_ * H_;
  const float* V = qkv + (size_t)2 * BT_ * H_;

  // stage q tile transposed, folding 1/sqrt(C)=1/32
#pragma unroll
  for (int i = 0; i < 4; ++i) {
    int idx = tid + i * 128;
    int r = idx >> 4;
    int h4 = (idx & 15) * 4;
    float4 v = *reinterpret_cast<const float4*>(
        &Q[((size_t)b * T_ + r0 + r) * H_ + h4]);
    qT[h4 + 0][r] = v.x * 0.03125f;
    qT[h4 + 1][r] = v.y * 0.03125f;
    qT[h4 + 2][r] = v.z * 0.03125f;
    qT[h4 + 3][r] = v.w * 0.03125f;
  }

  float m[4] = {-1e30f, -1e30f, -1e30f, -1e30f};
  float l[4] = {0, 0, 0, 0};
  float o[4][4];
#pragma unroll
  for (int r = 0; r < 4; ++r)
#pragma unroll
    for (int c = 0; c < 4; ++c) o[r][c] = 0.f;

  const int ktEnd = kt0 + nktp;
  for (int kt = kt0; kt < ktEnd; ++kt) {
    // stage K (transposed) + V (row-major): 16 float4/thread
#pragma unroll
    for (int i = 0; i < 8; ++i) {
      int idx = tid + i * 128;
      int j = idx >> 4;
      int h4 = (idx & 15) * 4;
      size_t gk = ((size_t)b * T_ + kt * 64 + j) * H_ + h4;
      float4 kv = *reinterpret_cast<const float4*>(&K[gk]);
      kT[h4 + 0][j] = kv.x;
      kT[h4 + 1][j] = kv.y;
      kT[h4 + 2][j] = kv.z;
      kT[h4 + 3][j] = kv.w;
      *reinterpret_cast<float4*>(&vl[j][h4]) =
          *reinterpret_cast<const float4*>(&V[gk]);
    }
    __syncthreads();   // covers qT on first iteration

    // S = q . k : 4 rows x 4 cols
    float s[4][4];
#pragma unroll
    for (int r = 0; r < 4; ++r)
#pragma unroll
      for (int c = 0; c < 4; ++c) s[r][c] = 0.f;
#pragma unroll 8
    for (int h = 0; h < 64; ++h) {
      const float4 qv = *reinterpret_cast<const float4*>(&qT[h][ty * 4]);
      const float4 kv = *reinterpret_cast<const float4*>(&kT[h][tx * 4]);
      const float qr[4] = {qv.x, qv.y, qv.z, qv.w};
      const float kr[4] = {kv.x, kv.y, kv.z, kv.w};
#pragma unroll
      for (int r = 0; r < 4; ++r)
#pragma unroll
        for (int c = 0; c < 4; ++c)
          s[r][c] = fmaf(qr[r], kr[c], s[r][c]);
    }

    // causal mask — only the last k-tile of a diagonal-holding piece clips
    if (masked && kt == ktEnd - 1) {
#pragma unroll
      for (int r = 0; r < 4; ++r) {
        const int row = r0 + ty * 4 + r;
#pragma unroll
        for (int c = 0; c < 4; ++c)
          if (kt * 64 + tx * 4 + c > row) s[r][c] = -1e30f;
      }
    }

    // online softmax per row; p written back into s
#pragma unroll
    for (int r = 0; r < 4; ++r) {
      float mt = fmaxf(fmaxf(s[r][0], s[r][1]), fmaxf(s[r][2], s[r][3]));
#pragma unroll
      for (int d = 1; d < 16; d <<= 1) mt = fmaxf(mt, __shfl_xor(mt, d));
      const float mn = fmaxf(m[r], mt);
      const float a = __expf(m[r] - mn);
      float sum = 0.f;
#pragma unroll
      for (int c = 0; c < 4; ++c) {
        s[r][c] = __expf(s[r][c] - mn);
        sum += s[r][c];
      }
#pragma unroll
      for (int d = 1; d < 16; d <<= 1) sum += __shfl_xor(sum, d);
      l[r] = l[r] * a + sum;
      m[r] = mn;
#pragma unroll
      for (int c = 0; c < 4; ++c) o[r][c] *= a;
    }

    // publish P transposed (b128 per key-col)
#pragma unroll
    for (int c = 0; c < 4; ++c) {
      *reinterpret_cast<float4*>(&pT[tx * 4 + c][ty * 4]) =
          make_float4(s[0][c], s[1][c], s[2][c], s[3][c]);
    }
    __syncthreads();

    // O += P . V
#pragma unroll 8
    for (int j = 0; j < 64; ++j) {
      const float4 pv = *reinterpret_cast<const float4*>(&pT[j][ty * 4]);
      const float4 vv = *reinterpret_cast<const float4*>(&vl[j][tx * 4]);
      const float pr[4] = {pv.x, pv.y, pv.z, pv.w};
      const float vr[4] = {vv.x, vv.y, vv.z, vv.w};
#pragma unroll
      for (int r = 0; r < 4; ++r)
#pragma unroll
        for (int c = 0; c < 4; ++c)
          o[r][c] = fmaf(pr[r], vr[c], o[r][c]);
    }
    __syncthreads();   // kT/vl/pT consumed before next stage
  }

  if (half < 0) {
    // unsplit: normalize and write out
#pragma unroll
    for (int r = 0; r < 4; ++r) {
      const float inv = 1.0f / l[r];
      *reinterpret_cast<float4*>(
          &out[((size_t)b * T_ + r0 + ty * 4 + r) * H_ + tx * 4]) =
          make_float4(o[r][0] * inv, o[r][1] * inv, o[r][2] * inv,
                      o[r][3] * inv);
    }
  } else {
    // split piece: write (m, l, O-numerator) partials
    const int pidx = half * 256 + b * 32 + (qt - 32);
#pragma unroll
    for (int r = 0; r < 4; ++r) {
      const int row = ty * 4 + r;
      *reinterpret_cast<float4*>(
          &ws[PO_F + ((size_t)pidx * 32 + row) * 64 + tx * 4]) =
          make_float4(o[r][0], o[r][1], o[r][2], o[r][3]);
      if (tx == 0) {
        ws[PM_F + pidx * 32 + row] = m[r];
        ws[PL_F + pidx * 32 + row] = l[r];
      }
    }
  }
}

// ---------------------------------------------------------------------------
// Kernel 3: merge split-K partials for rows qt in [32,64). 512 x 256 thr,
// one thread per (row, 4 h-cols). ~8 MB traffic, memory-bound, ~3 us.
// ---------------------------------------------------------------------------
__global__ __launch_bounds__(256) void attn_combine(
    const float* __restrict__ ws, float* __restrict__ out) {
  const int gid = blockIdx.x * 256 + threadIdx.x;   // 131072
  const int rowid = gid >> 4;                       // 0..8191
  const int h4 = (gid & 15) * 4;
  const int b = rowid >> 10;
  const int rem = rowid & 1023;
  const int qt = 32 + (rem >> 5);
  const int r = rem & 31;
  const int p = b * 32 + (qt - 32);
  const int pa = p, pb = 256 + p;

  const float mA = ws[PM_F + pa * 32 + r], mB = ws[PM_F + pb * 32 + r];
  const float lA = ws[PL_F + pa * 32 + r], lB = ws[PL_F + pb * 32 + r];
  const float mm = fmaxf(mA, mB);
  const float sA = __expf(mA - mm), sB = __expf(mB - mm);
  const float inv = 1.0f / (lA * sA + lB * sB);
  const float4 oA = *reinterpret_cast<const float4*>(
      &ws[PO_F + ((size_t)pa * 32 + r) * 64 + h4]);
  const float4 oB = *reinterpret_cast<const float4*>(
      &ws[PO_F + ((size_t)pb * 32 + r) * 64 + h4]);
  *reinterpret_cast<float4*>(
      &out[((size_t)b * T_ + qt * 32 + r) * H_ + h4]) =
      make_float4((oA.x * sA + oB.x * sB) * inv, (oA.y * sA + oB.y * sB) * inv,
                  (oA.z * sA + oB.z * sB) * inv, (oA.w * sA + oB.w * sB) * inv);
}

extern "C" void kernel_launch(void* const* d_in, const int* in_sizes, int n_in,
                              void* d_out, int out_size, void* d_ws,
                              size_t ws_size, hipStream_t stream) {
  const float* x  = (const float*)d_in[0];
  const float* Wq = (const float*)d_in[1];
  const float* Wk = (const float*)d_in[2];
  const float* Wv = (const float*)d_in[3];
  float* ws  = (float*)d_ws;   // QKV planes + split partials (~17 MB)
  float* out = (float*)d_out;

  qkv_proj<<<512, 128, 0, stream>>>(x, Wq, Wk, Wv, ws);
  attn_fwd<<<768, 128, 0, stream>>>(ws, out, ws);
  attn_combine<<<512, 256, 0, stream>>>(ws, out);
}